// Round 1
// baseline (3563.091 us; speedup 1.0000x reference)
//
#include <hip/hip_runtime.h>
#include <math.h>

// ---- problem constants (from setup_inputs) ----
// B=8, Cin=256, H=W=128, RC=128, NC=12, HD=64, NL=3, E=132
#define BNS_F 0.9999950000374998f

// =====================================================================
// Kernel A: masks = (maxpool3x3(seg) > 0.5), mask_sum[b,c] = sum(masks)
// grid: B*NC*H blocks, 128 threads (one per column)
// =====================================================================
__global__ __launch_bounds__(128) void masks_kernel(
    const float* __restrict__ seg, float* __restrict__ masks,
    float* __restrict__ mask_sum)
{
    int bid = blockIdx.x;
    int h = bid & 127;
    int c = (bid >> 7) % 12;
    int b = bid / (128 * 12);
    int px = threadIdx.x;

    const float* s = seg + ((size_t)(b * 12 + c) * 128) * 128;
    float m = -INFINITY;
    #pragma unroll
    for (int dy = -1; dy <= 1; ++dy) {
        int y = h + dy;
        if (y < 0 || y > 127) continue;
        #pragma unroll
        for (int dx = -1; dx <= 1; ++dx) {
            int x = px + dx;
            if (x < 0 || x > 127) continue;
            m = fmaxf(m, s[y * 128 + x]);
        }
    }
    float v = (m > 0.5f) ? 1.0f : 0.0f;
    masks[((size_t)(b * 12 + c) * 128 + h) * 128 + px] = v;

    float cnt = v;
    #pragma unroll
    for (int off = 1; off < 64; off <<= 1) cnt += __shfl_xor(cnt, off, 64);
    if ((threadIdx.x & 63) == 0) atomicAdd(&mask_sum[b * 12 + c], cnt);
}

// =====================================================================
// Kernel B: fused 3x3 conv (256->128) + bias/BNS/ReLU + 1x1 (128->64)
//           + bias/BNS/ReLU + masked per-class accumulation.
// grid: B*H*2 blocks (half-row of 64 px each), 256 threads = 4 waves.
// wave w owns output channels [w*32, w*32+32) in phase 1,
//        node dims [w*16, w*16+16) in phase 2; lane = pixel.
// =====================================================================
__global__ __launch_bounds__(256) void conv_node_kernel(
    const float* __restrict__ feat, const float* __restrict__ Wrpn,
    const float* __restrict__ brpn, const float* __restrict__ Wnode,
    const float* __restrict__ bnode, const float* __restrict__ masks,
    float* __restrict__ masked_sum)
{
    __shared__ float smem[128 * 64];   // 32 KB; phase1 feats use first 1584 floats

    int bid = blockIdx.x;
    int wt = bid & 1;
    int h  = (bid >> 1) & 127;
    int b  = bid >> 8;
    int px0 = wt * 64;

    int t = threadIdx.x;
    int lane = t & 63;
    int wv = __builtin_amdgcn_readfirstlane(t >> 6);   // force wave-uniform (scalar)

    float acc[32];
    #pragma unroll
    for (int j = 0; j < 32; ++j) acc[j] = 0.f;

    // ---- phase 1: 3x3 conv over input-channel chunks of 8 ----
    for (int ic0 = 0; ic0 < 256; ic0 += 8) {
        // stage feats: 8 ch x 3 rows x 66 cols (with zero halo)
        for (int i = t; i < 8 * 3 * 66; i += 256) {
            int ic = i / 198;
            int rr = (i / 66) % 3;
            int cc = i % 66;
            int gy = h - 1 + rr;
            int gx = px0 - 1 + cc;
            float v = 0.f;
            if (gy >= 0 && gy < 128 && gx >= 0 && gx < 128)
                v = feat[(((size_t)b * 256 + ic0 + ic) * 128 + gy) * 128 + gx];
            smem[i] = v;
        }
        __syncthreads();

        for (int ic = 0; ic < 8; ++ic) {
            float f[9];
            const float* fs = &smem[ic * 198 + lane];
            #pragma unroll
            for (int rr = 0; rr < 3; ++rr)
                #pragma unroll
                for (int dd = 0; dd < 3; ++dd)
                    f[rr * 3 + dd] = fs[rr * 66 + dd];

            // wave-uniform weight base -> scalar loads
            const float* wb = Wrpn + (size_t)(wv * 32) * 2304 + (size_t)(ic0 + ic) * 9;
            #pragma unroll
            for (int j = 0; j < 32; ++j) {
                const float* wj = wb + (size_t)j * 2304;
                #pragma unroll
                for (int tap = 0; tap < 9; ++tap)
                    acc[j] = fmaf(wj[tap], f[tap], acc[j]);
            }
        }
        __syncthreads();
    }

    // ---- write refined tile (post bias/BNS/ReLU) to LDS as [oc][px] ----
    #pragma unroll
    for (int j = 0; j < 32; ++j) {
        int oc = wv * 32 + j;
        float r = fmaxf((acc[j] + brpn[oc]) * BNS_F, 0.f);
        smem[oc * 64 + lane] = r;
    }
    __syncthreads();

    // ---- phase 2: z = relu((W_node @ refined + b_node)*BNS), 16 dims/wave ----
    float z[16];
    #pragma unroll
    for (int j = 0; j < 16; ++j) z[j] = 0.f;
    const float* wn = Wnode + (size_t)(wv * 16) * 128;
    for (int k = 0; k < 128; ++k) {
        float rv = smem[k * 64 + lane];
        #pragma unroll
        for (int j = 0; j < 16; ++j)
            z[j] = fmaf(wn[j * 128 + k], rv, z[j]);
    }
    #pragma unroll
    for (int j = 0; j < 16; ++j)
        z[j] = fmaxf((z[j] + bnode[wv * 16 + j]) * BNS_F, 0.f);

    // ---- masked accumulation into masked_sum[b][c][d] ----
    const float* mrow = masks + ((size_t)b * 12 * 128 + h) * 128 + px0;
    float* msb = masked_sum + (size_t)b * 12 * 64;
    for (int c = 0; c < 12; ++c) {
        float m = mrow[(size_t)c * 16384 + lane];
        #pragma unroll
        for (int j = 0; j < 16; ++j) {
            float v = z[j] * m;
            #pragma unroll
            for (int off = 1; off < 64; off <<= 1) v += __shfl_xor(v, off, 64);
            if (lane == j) atomicAdd(&msb[c * 64 + wv * 16 + j], v);
        }
    }
}

// =====================================================================
// Kernel C: node_feats -> edges -> 3-layer GNN -> xs = x_final @ W_sp
// grid: B blocks, 256 threads. All tiny; one block per batch.
// =====================================================================
__global__ __launch_bounds__(256) void graph_kernel(
    const float* __restrict__ masked_sum, const float* __restrict__ mask_sum,
    const float* __restrict__ We1, const float* __restrict__ be1,
    const float* __restrict__ We2, const float* __restrict__ be2,
    const float* __restrict__ Wg, const float* __restrict__ bg,
    const float* __restrict__ lng, const float* __restrict__ lnb,
    const float* __restrict__ glob, const float* __restrict__ Wsp,
    float* __restrict__ xs_out)
{
    __shared__ float nf[12 * 64];     // node feats; later reused as xnew temp
    __shared__ float x [12 * 64];
    __shared__ float xw[12 * 64];
    __shared__ float ea[132 * 64];
    __shared__ float present[12];
    __shared__ float presence[12];

    int b = blockIdx.x;
    int t = threadIdx.x;
    int lane = t & 63;
    int wv = t >> 6;

    // node_feats = masked_sum / (mask_sum + 1e-6)
    for (int i = t; i < 768; i += 256) {
        float ms = mask_sum[b * 12 + (i >> 6)];
        nf[i] = masked_sum[b * 768 + i] / (ms + 1e-6f);
    }
    if (t < 12) present[t] = (mask_sum[b * 12 + t] > 0.f) ? 1.f : 0.f;
    __syncthreads();

    // presence[c] = (sum_d nf[c][d] != 0); also init x = nf
    for (int i = t; i < 768; i += 256) {
        int c = i >> 6;
        float v = nf[i];
        #pragma unroll
        for (int off = 1; off < 64; off <<= 1) v += __shfl_xor(v, off, 64);
        if ((i & 63) == 0) presence[c] = (v != 0.f) ? 1.f : 0.f;
        x[i] = nf[i];
    }
    __syncthreads();

    // edges: one wave per edge; lane = output dim d
    for (int e = wv; e < 132; e += 4) {
        int src = e / 11;
        int jj = e % 11;
        int dst = jj + (jj >= src ? 1 : 0);
        int d = lane;
        float hv = be1[d];
        const float* nsrc = &nf[src * 64];
        const float* ndst = &nf[dst * 64];
        for (int k = 0; k < 64; ++k) hv = fmaf(nsrc[k], We1[k * 64 + d], hv);
        for (int k = 0; k < 64; ++k) hv = fmaf(ndst[k], We1[(64 + k) * 64 + d], hv);
        hv = fmaxf(hv, 0.f);
        float av = be2[d];
        for (int k = 0; k < 64; ++k) {
            float hk = __shfl(hv, k, 64);
            av = fmaf(hk, We2[k * 64 + d], av);
        }
        float valid = present[src] * present[dst];
        ea[e * 64 + d] = av * valid;
    }
    __syncthreads();

    // 3 GNN layers
    for (int l = 0; l < 3; ++l) {
        const float* wg = Wg + l * 4096;
        for (int i = t; i < 768; i += 256) {
            int c = i >> 6, d = i & 63;
            float v = 0.f;
            for (int k = 0; k < 64; ++k) v = fmaf(x[c * 64 + k], wg[k * 64 + d], v);
            xw[i] = v;
        }
        __syncthreads();
        for (int i = t; i < 768; i += 256) {
            int j = i >> 6, d = i & 63;
            float agg = bg[l * 64 + d];
            #pragma unroll
            for (int src2 = 0; src2 < 12; ++src2) {
                if (src2 == j) continue;
                int jj2 = j - (j > src2 ? 1 : 0);
                int e = src2 * 11 + jj2;
                agg = fmaf(xw[src2 * 64 + d], ea[e * 64 + d], agg);
            }
            float xr = fmaxf(agg, 0.f);
            // LayerNorm over d (one c per wave)
            float s = xr;
            #pragma unroll
            for (int off = 1; off < 64; off <<= 1) s += __shfl_xor(s, off, 64);
            float mu = s * (1.f / 64.f);
            float df = xr - mu;
            float s2 = df * df;
            #pragma unroll
            for (int off = 1; off < 64; off <<= 1) s2 += __shfl_xor(s2, off, 64);
            float var = s2 * (1.f / 64.f);
            float normed = df * (1.0f / sqrtf(var + 1e-5f)) * lng[l * 64 + d] + lnb[l * 64 + d];
            float xnew = (l > 0) ? (normed + x[i]) : normed;
            nf[i] = xnew;             // nf reused as temp (dead after edges)
        }
        __syncthreads();
        for (int i = t; i < 768; i += 256) x[i] = nf[i];
        __syncthreads();
    }

    // x_final = x*presence + glob*(1-presence)
    for (int i = t; i < 768; i += 256) {
        int c = i >> 6;
        float p = presence[c];
        x[i] = x[i] * p + glob[i & 1023 ? i : i] * 0.f + glob[c * 64 + (i & 63)] * (1.f - p) + 0.f * p; // see below
    }
    __syncthreads();

    // xs[c][o] = sum_d x[c][d] * Wsp[d][o]
    for (int i = t; i < 12 * 128; i += 256) {
        int c = i >> 7, o = i & 127;
        float v = 0.f;
        for (int k = 0; k < 64; ++k) v = fmaf(x[c * 64 + k], Wsp[k * 128 + o], v);
        xs_out[b * 1536 + i] = v;
    }
}

// =====================================================================
// Kernel D: out[b,o,h,w] = relu((sum_c xs[b,c,o]*mask[b,c,h,w] + b_sp[o])*BNS)
// grid: B*H blocks (one row), 256 threads.
// =====================================================================
__global__ __launch_bounds__(256) void out_kernel(
    const float* __restrict__ xs, const float* __restrict__ masks,
    const float* __restrict__ bsp, float* __restrict__ out)
{
    __shared__ float xsl[12 * 128];
    __shared__ float ml[12 * 128];
    int bid = blockIdx.x;
    int h = bid & 127;
    int b = bid >> 7;
    int t = threadIdx.x;

    for (int i = t; i < 1536; i += 256) xsl[i] = xs[b * 1536 + i];
    for (int i = t; i < 1536; i += 256) {
        int c = i >> 7, px = i & 127;
        ml[i] = masks[((size_t)(b * 12 + c) * 128 + h) * 128 + px];
    }
    __syncthreads();

    int px = t & 127;
    int og = t >> 7;
    float m[12];
    #pragma unroll
    for (int c = 0; c < 12; ++c) m[c] = ml[c * 128 + px];

    float* ob = out + ((size_t)b * 128 * 128 + h) * 128 + px;
    for (int i = 0; i < 64; ++i) {
        int o = og * 64 + i;
        float s = 0.f;
        #pragma unroll
        for (int c = 0; c < 12; ++c) s = fmaf(xsl[c * 128 + o], m[c], s);
        ob[(size_t)o * 16384] = fmaxf((s + bsp[o]) * BNS_F, 0.f);
    }
}

// =====================================================================
extern "C" void kernel_launch(void* const* d_in, const int* in_sizes, int n_in,
                              void* d_out, int out_size, void* d_ws, size_t ws_size,
                              hipStream_t stream)
{
    const float* feat  = (const float*)d_in[0];
    const float* seg   = (const float*)d_in[1];
    const float* Wrpn  = (const float*)d_in[2];
    const float* brpn  = (const float*)d_in[3];
    const float* Wnode = (const float*)d_in[4];
    const float* bnode = (const float*)d_in[5];
    const float* We1   = (const float*)d_in[6];
    const float* be1   = (const float*)d_in[7];
    const float* We2   = (const float*)d_in[8];
    const float* be2   = (const float*)d_in[9];
    const float* Wg    = (const float*)d_in[10];
    const float* bg    = (const float*)d_in[11];
    const float* lng   = (const float*)d_in[12];
    const float* lnb   = (const float*)d_in[13];
    const float* glob  = (const float*)d_in[14];
    const float* Wsp   = (const float*)d_in[15];
    const float* bsp   = (const float*)d_in[16];
    float* out = (float*)d_out;

    // workspace layout (floats): masks | masked_sum | mask_sum | xs
    float* masks      = (float*)d_ws;            // 8*12*128*128 = 1,572,864
    float* masked_sum = masks + 1572864;         // 8*12*64 = 6144
    float* mask_sum   = masked_sum + 6144;       // 96
    float* xs         = mask_sum + 96;           // 8*12*128 = 12288

    hipMemsetAsync(masked_sum, 0, (6144 + 96) * sizeof(float), stream);

    masks_kernel<<<8 * 12 * 128, 128, 0, stream>>>(seg, masks, mask_sum);
    conv_node_kernel<<<2048, 256, 0, stream>>>(feat, Wrpn, brpn, Wnode, bnode,
                                               masks, masked_sum);
    graph_kernel<<<8, 256, 0, stream>>>(masked_sum, mask_sum, We1, be1, We2, be2,
                                        Wg, bg, lng, lnb, glob, Wsp, xs);
    out_kernel<<<1024, 256, 0, stream>>>(xs, masks, bsp, out);
}

// Round 2
// 647.513 us; speedup vs baseline: 5.5027x; 5.5027x over previous
//
#include <hip/hip_runtime.h>
#include <math.h>

// B=8, Cin=256, H=W=128, RC=128, NC=12, HD=64, NL=3, E=132
#define BNS_F 0.9999950000374998f

typedef short short8 __attribute__((ext_vector_type(8)));   // 8 bf16 (4 VGPRs)
typedef float f32x4 __attribute__((ext_vector_type(4)));    // MFMA C/D frag
typedef __attribute__((address_space(3))) void lds_void;
typedef const __attribute__((address_space(1))) void glb_void;

__device__ __forceinline__ unsigned short f2bf(float f) {
    unsigned u = __builtin_bit_cast(unsigned, f);
    unsigned r = (u + 0x7fffu + ((u >> 16) & 1u)) >> 16;   // RNE
    return (unsigned short)r;
}

// =====================================================================
// convert features fp32 [b][ic][px] -> bf16 pixel-major [b][px][ic]
// block: 64 px x 256 ic; read coalesced, LDS transpose, write coalesced
// =====================================================================
__global__ __launch_bounds__(256) void convert_feat(
    const float* __restrict__ feat, unsigned short* __restrict__ Fbt)
{
    __shared__ unsigned short sb[64 * 264];     // 264 = 256 + pad (16B-aligned rows)
    int bid = blockIdx.x;                       // 8 * 256
    int b = bid >> 8;
    int px0 = (bid & 255) * 64;
    int t = threadIdx.x, l = t & 63, w = t >> 6;

    for (int r = 0; r < 64; ++r) {
        int ic = r * 4 + w;
        float v = feat[((size_t)(b * 256 + ic)) * 16384 + px0 + l];
        sb[l * 264 + ic] = f2bf(v);
    }
    __syncthreads();

    int px = t >> 2, q = t & 3;                 // 64 px x 4 chunks of 128B
    const uint4* srcp = (const uint4*)(sb + px * 264 + q * 64);
    uint4* dstp = (uint4*)(Fbt + ((size_t)(b * 16384 + px0 + px)) * 256 + q * 64);
    #pragma unroll
    for (int j = 0; j < 8; ++j) dstp[j] = srcp[j];
}

// =====================================================================
// reorg W_rpn[oc][ic][tap] fp32 -> Wr[tap][oc][ic] bf16
// =====================================================================
__global__ __launch_bounds__(256) void reorg_w(
    const float* __restrict__ Wrpn, unsigned short* __restrict__ Wr)
{
    int oc = blockIdx.x;            // 128
    int ic = threadIdx.x;           // 256
    const float* src = Wrpn + ((size_t)oc * 256 + ic) * 9;
    #pragma unroll
    for (int tap = 0; tap < 9; ++tap)
        Wr[((size_t)tap * 128 + oc) * 256 + ic] = f2bf(src[tap]);
}

// =====================================================================
// masks = (maxpool3x3(seg) > 0.5), mask_sum[b,c]
// =====================================================================
__global__ __launch_bounds__(128) void masks_kernel(
    const float* __restrict__ seg, float* __restrict__ masks,
    float* __restrict__ mask_sum)
{
    int bid = blockIdx.x;
    int h = bid & 127;
    int c = (bid >> 7) % 12;
    int b = bid / (128 * 12);
    int px = threadIdx.x;

    const float* s = seg + ((size_t)(b * 12 + c) * 128) * 128;
    float m = -INFINITY;
    #pragma unroll
    for (int dy = -1; dy <= 1; ++dy) {
        int y = h + dy;
        if (y < 0 || y > 127) continue;
        #pragma unroll
        for (int dx = -1; dx <= 1; ++dx) {
            int x = px + dx;
            if (x < 0 || x > 127) continue;
            m = fmaxf(m, s[y * 128 + x]);
        }
    }
    float v = (m > 0.5f) ? 1.0f : 0.0f;
    masks[((size_t)(b * 12 + c) * 128 + h) * 128 + px] = v;

    float cnt = v;
    #pragma unroll
    for (int off = 1; off < 64; off <<= 1) cnt += __shfl_xor(cnt, off, 64);
    if ((threadIdx.x & 63) == 0) atomicAdd(&mask_sum[b * 12 + c], cnt);
}

// =====================================================================
// MFMA implicit-GEMM conv (3x3, 256->128) + bias/BNS/ReLU
//   + 1x1 (128->64) + bias/BNS/ReLU + masked per-class sums.
// grid: 1024 = B x H. 512 threads = 8 waves; wave = 32oc x 64px.
// K-loop: 8 chunks of 32 ic; per chunk 9 taps; double-buffered LDS
// staged via global_load_lds (16B) with slot swizzle on global source.
// =====================================================================
#define SWZ(col) (((col) >> 1) & 3)
#define BUF_BYTES 24960   // 1560 chunks * 16B (3 rows * 130 cols * 4 slots)

__global__ __launch_bounds__(512) void conv_node_kernel(
    const unsigned short* __restrict__ Fbt, const unsigned short* __restrict__ Wr,
    const float* __restrict__ brpn, const float* __restrict__ Wnode,
    const float* __restrict__ bnode, const float* __restrict__ masks,
    const float* __restrict__ zero16, float* __restrict__ masked_sum)
{
    __shared__ __align__(16) unsigned char lds[65536];
    int bid = blockIdx.x;
    int h = bid & 127, b = bid >> 7;
    int t = threadIdx.x;
    int lane = t & 63;
    int wv = __builtin_amdgcn_readfirstlane(t >> 6);  // 0..7, wave-uniform
    int mg = wv >> 1;        // oc group: oc0 = mg*32
    int ng = wv & 1;         // px group: px0 = ng*64
    int kg = lane >> 4;      // k-group 0..3
    int ln15 = lane & 15;

    f32x4 acc[2][4];
    #pragma unroll
    for (int i = 0; i < 2; ++i)
        #pragma unroll
        for (int j = 0; j < 4; ++j) acc[i][j] = (f32x4){0.f, 0.f, 0.f, 0.f};

    const size_t fb_base = (size_t)b * 16384 * 256;

    // ---- staging: LDS linear chunks, pre-swizzled global source ----
    auto stage = [&](int bsel, int ic0) {
        for (int c0 = 0; c0 < 1560; c0 += 512) {
            int c = c0 + t;
            unsigned ldsoff = (unsigned)bsel * BUF_BYTES + (unsigned)(c0 + wv * 64) * 16;
            if (c < 1560) {
                int sp  = c & 3;              // physical slot
                int cr  = c >> 2;
                int col = cr % 130;
                int row = cr / 130;           // 0..2  (y = h-1+row)
                int sl  = (sp - SWZ(col)) & 3;  // logical slot -> ic offset
                int y = h - 1 + row;
                int x = col - 1;
                const void* gsrc;
                if ((unsigned)y < 128u && (unsigned)x < 128u)
                    gsrc = (const void*)(Fbt + fb_base + (size_t)(y * 128 + x) * 256
                                         + ic0 + sl * 8);
                else
                    gsrc = (const void*)zero16;
                __builtin_amdgcn_global_load_lds(
                    (glb_void*)gsrc, (lds_void*)(lds + ldsoff), 16, 0, 0);
            }
        }
    };

    stage(0, 0);
    __syncthreads();

    for (int s = 0; s < 8; ++s) {
        if (s < 7) stage((s + 1) & 1, (s + 1) * 32);
        const unsigned char* buf = lds + (s & 1) * BUF_BYTES;
        int ic0 = s * 32;

        #pragma unroll
        for (int dy = 0; dy < 3; ++dy) {
            #pragma unroll
            for (int dxi = 0; dxi < 3; ++dxi) {
                int tap = dy * 3 + dxi;
                const unsigned short* wp =
                    Wr + ((size_t)(tap * 128 + mg * 32 + ln15) * 256 + ic0 + kg * 8);
                short8 a0 = *(const short8*)wp;
                short8 a1 = *(const short8*)(wp + (size_t)16 * 256);
                short8 bf[4];
                #pragma unroll
                for (int nt = 0; nt < 4; ++nt) {
                    int col = ng * 64 + nt * 16 + ln15 + dxi;
                    unsigned off =
                        (unsigned)((dy * 130 + col) * 4 + ((kg + SWZ(col)) & 3)) * 16;
                    bf[nt] = *(const short8*)(buf + off);
                }
                #pragma unroll
                for (int nt = 0; nt < 4; ++nt) {
                    acc[0][nt] = __builtin_amdgcn_mfma_f32_16x16x32_bf16(
                        a0, bf[nt], acc[0][nt], 0, 0, 0);
                    acc[1][nt] = __builtin_amdgcn_mfma_f32_16x16x32_bf16(
                        a1, bf[nt], acc[1][nt], 0, 0, 0);
                }
            }
        }
        __syncthreads();   // drains stage(s+1) loads + barrier
    }

    // ---- epilogue: refined (post bias/BNS/ReLU) into LDS [128 oc][128 px] ----
    float* refined = (float*)lds;
    #pragma unroll
    for (int mt = 0; mt < 2; ++mt) {
        #pragma unroll
        for (int nt = 0; nt < 4; ++nt) {
            int px = ng * 64 + nt * 16 + ln15;
            #pragma unroll
            for (int r = 0; r < 4; ++r) {
                int oc = mg * 32 + mt * 16 + kg * 4 + r;   // D: row=(lane>>4)*4+r
                float v = fmaxf((acc[mt][nt][r] + brpn[oc]) * BNS_F, 0.f);
                refined[oc * 128 + px] = v;
            }
        }
    }
    __syncthreads();

    // ---- phase 2: z = relu((W_node @ refined + b)*BNS); wave -> 8 dims ----
    float z0[8], z1[8];
    #pragma unroll
    for (int j = 0; j < 8; ++j) { z0[j] = 0.f; z1[j] = 0.f; }
    const float* wn = Wnode + (size_t)wv * 8 * 128;
    for (int k = 0; k < 128; ++k) {
        float r0 = refined[k * 128 + lane];
        float r1 = refined[k * 128 + 64 + lane];
        #pragma unroll
        for (int j = 0; j < 8; ++j) {
            float w = wn[j * 128 + k];
            z0[j] = fmaf(w, r0, z0[j]);
            z1[j] = fmaf(w, r1, z1[j]);
        }
    }
    #pragma unroll
    for (int j = 0; j < 8; ++j) {
        float bb = bnode[wv * 8 + j];
        z0[j] = fmaxf((z0[j] + bb) * BNS_F, 0.f);
        z1[j] = fmaxf((z1[j] + bb) * BNS_F, 0.f);
    }

    // ---- masked accumulation ----
    const float* mrow = masks + ((size_t)b * 12 * 128 + h) * 128;
    float* msb = masked_sum + (size_t)b * 768 + wv * 8;
    for (int c = 0; c < 12; ++c) {
        float m0 = mrow[(size_t)c * 16384 + lane];
        float m1 = mrow[(size_t)c * 16384 + 64 + lane];
        #pragma unroll
        for (int j = 0; j < 8; ++j) {
            float v = fmaf(z0[j], m0, z1[j] * m1);
            #pragma unroll
            for (int off2 = 1; off2 < 64; off2 <<= 1) v += __shfl_xor(v, off2, 64);
            if (lane == 0) atomicAdd(&msb[c * 64 + j], v);
        }
    }
}

// =====================================================================
// graph: node_feats -> edges -> 3-layer GNN -> xs = x_final @ W_sp
// =====================================================================
__global__ __launch_bounds__(256) void graph_kernel(
    const float* __restrict__ masked_sum, const float* __restrict__ mask_sum,
    const float* __restrict__ We1, const float* __restrict__ be1,
    const float* __restrict__ We2, const float* __restrict__ be2,
    const float* __restrict__ Wg, const float* __restrict__ bg,
    const float* __restrict__ lng, const float* __restrict__ lnb,
    const float* __restrict__ glob, const float* __restrict__ Wsp,
    float* __restrict__ xs_out)
{
    __shared__ float nf[12 * 64];
    __shared__ float x [12 * 64];
    __shared__ float xw[12 * 64];
    __shared__ float ea[132 * 64];
    __shared__ float present[12];
    __shared__ float presence[12];

    int b = blockIdx.x;
    int t = threadIdx.x;
    int wv = t >> 6;

    for (int i = t; i < 768; i += 256) {
        float ms = mask_sum[b * 12 + (i >> 6)];
        nf[i] = masked_sum[b * 768 + i] / (ms + 1e-6f);
    }
    if (t < 12) present[t] = (mask_sum[b * 12 + t] > 0.f) ? 1.f : 0.f;
    __syncthreads();

    for (int i = t; i < 768; i += 256) {
        int c = i >> 6;
        float v = nf[i];
        #pragma unroll
        for (int off = 1; off < 64; off <<= 1) v += __shfl_xor(v, off, 64);
        if ((i & 63) == 0) presence[c] = (v != 0.f) ? 1.f : 0.f;
        x[i] = nf[i];
    }
    __syncthreads();

    for (int e = wv; e < 132; e += 4) {
        int src = e / 11;
        int jj = e % 11;
        int dst = jj + (jj >= src ? 1 : 0);
        int d = t & 63;
        float hv = be1[d];
        const float* nsrc = &nf[src * 64];
        const float* ndst = &nf[dst * 64];
        for (int k = 0; k < 64; ++k) hv = fmaf(nsrc[k], We1[k * 64 + d], hv);
        for (int k = 0; k < 64; ++k) hv = fmaf(ndst[k], We1[(64 + k) * 64 + d], hv);
        hv = fmaxf(hv, 0.f);
        float av = be2[d];
        for (int k = 0; k < 64; ++k) {
            float hk = __shfl(hv, k, 64);
            av = fmaf(hk, We2[k * 64 + d], av);
        }
        ea[e * 64 + d] = av * present[src] * present[dst];
    }
    __syncthreads();

    for (int l = 0; l < 3; ++l) {
        const float* wg = Wg + l * 4096;
        for (int i = t; i < 768; i += 256) {
            int c = i >> 6, d = i & 63;
            float v = 0.f;
            for (int k = 0; k < 64; ++k) v = fmaf(x[c * 64 + k], wg[k * 64 + d], v);
            xw[i] = v;
        }
        __syncthreads();
        for (int i = t; i < 768; i += 256) {
            int j = i >> 6, d = i & 63;
            float agg = bg[l * 64 + d];
            #pragma unroll
            for (int src2 = 0; src2 < 12; ++src2) {
                if (src2 == j) continue;
                int jj2 = j - (j > src2 ? 1 : 0);
                int e = src2 * 11 + jj2;
                agg = fmaf(xw[src2 * 64 + d], ea[e * 64 + d], agg);
            }
            float xr = fmaxf(agg, 0.f);
            float s = xr;
            #pragma unroll
            for (int off = 1; off < 64; off <<= 1) s += __shfl_xor(s, off, 64);
            float mu = s * (1.f / 64.f);
            float df = xr - mu;
            float s2 = df * df;
            #pragma unroll
            for (int off = 1; off < 64; off <<= 1) s2 += __shfl_xor(s2, off, 64);
            float var = s2 * (1.f / 64.f);
            float normed = df * (1.0f / sqrtf(var + 1e-5f)) * lng[l * 64 + d]
                           + lnb[l * 64 + d];
            nf[i] = (l > 0) ? (normed + x[i]) : normed;
        }
        __syncthreads();
        for (int i = t; i < 768; i += 256) x[i] = nf[i];
        __syncthreads();
    }

    for (int i = t; i < 768; i += 256) {
        int c = i >> 6;
        float p = presence[c];
        x[i] = x[i] * p + glob[c * 64 + (i & 63)] * (1.f - p);
    }
    __syncthreads();

    for (int i = t; i < 12 * 128; i += 256) {
        int c = i >> 7, o = i & 127;
        float v = 0.f;
        for (int k = 0; k < 64; ++k) v = fmaf(x[c * 64 + k], Wsp[k * 128 + o], v);
        xs_out[b * 1536 + i] = v;
    }
}

// =====================================================================
// out[b,o,h,w] = relu((sum_c xs[b,c,o]*mask[b,c,h,w] + b_sp[o])*BNS)
// =====================================================================
__global__ __launch_bounds__(256) void out_kernel(
    const float* __restrict__ xs, const float* __restrict__ masks,
    const float* __restrict__ bsp, float* __restrict__ out)
{
    __shared__ float xsl[12 * 128];
    __shared__ float ml[12 * 128];
    int bid = blockIdx.x;
    int h = bid & 127;
    int b = bid >> 7;
    int t = threadIdx.x;

    for (int i = t; i < 1536; i += 256) xsl[i] = xs[b * 1536 + i];
    for (int i = t; i < 1536; i += 256) {
        int c = i >> 7, px = i & 127;
        ml[i] = masks[((size_t)(b * 12 + c) * 128 + h) * 128 + px];
    }
    __syncthreads();

    int px = t & 127;
    int og = t >> 7;
    float m[12];
    #pragma unroll
    for (int c = 0; c < 12; ++c) m[c] = ml[c * 128 + px];

    float* ob = out + ((size_t)b * 128 * 128 + h) * 128 + px;
    for (int i = 0; i < 64; ++i) {
        int o = og * 64 + i;
        float s = 0.f;
        #pragma unroll
        for (int c = 0; c < 12; ++c) s = fmaf(xsl[c * 128 + o], m[c], s);
        ob[(size_t)o * 16384] = fmaxf((s + bsp[o]) * BNS_F, 0.f);
    }
}

// =====================================================================
extern "C" void kernel_launch(void* const* d_in, const int* in_sizes, int n_in,
                              void* d_out, int out_size, void* d_ws, size_t ws_size,
                              hipStream_t stream)
{
    const float* feat  = (const float*)d_in[0];
    const float* seg   = (const float*)d_in[1];
    const float* Wrpn  = (const float*)d_in[2];
    const float* brpn  = (const float*)d_in[3];
    const float* Wnode = (const float*)d_in[4];
    const float* bnode = (const float*)d_in[5];
    const float* We1   = (const float*)d_in[6];
    const float* be1   = (const float*)d_in[7];
    const float* We2   = (const float*)d_in[8];
    const float* be2   = (const float*)d_in[9];
    const float* Wg    = (const float*)d_in[10];
    const float* bg    = (const float*)d_in[11];
    const float* lng   = (const float*)d_in[12];
    const float* lnb   = (const float*)d_in[13];
    const float* glob  = (const float*)d_in[14];
    const float* Wsp   = (const float*)d_in[15];
    const float* bsp   = (const float*)d_in[16];
    float* out = (float*)d_out;

    // Fbt (bf16 features, pixel-major) lives in d_out: 33.55M bf16 = 67.1 MB
    // = exactly out_size*4 bytes; fully consumed by conv before out_kernel.
    unsigned short* Fbt = (unsigned short*)d_out;

    // workspace (floats): masks | masked_sum | mask_sum | zero16 | xs | Wr(bf16)
    float* masks      = (float*)d_ws;            // 1,572,864
    float* masked_sum = masks + 1572864;         // 6144
    float* mask_sum   = masked_sum + 6144;       // 96
    float* zero16     = mask_sum + 96;           // 8 (16B zero stub)
    float* xs         = zero16 + 8;              // 12288
    unsigned short* Wr = (unsigned short*)(xs + 12288);  // 294,912 bf16

    hipMemsetAsync(masked_sum, 0, (6144 + 96 + 8) * sizeof(float), stream);

    convert_feat<<<2048, 256, 0, stream>>>(feat, Fbt);
    reorg_w<<<128, 256, 0, stream>>>(Wrpn, Wr);
    masks_kernel<<<8 * 12 * 128, 128, 0, stream>>>(seg, masks, mask_sum);
    conv_node_kernel<<<1024, 512, 0, stream>>>(Fbt, Wr, brpn, Wnode, bnode,
                                               masks, zero16, masked_sum);
    graph_kernel<<<8, 256, 0, stream>>>(masked_sum, mask_sum, We1, be1, We2, be2,
                                        Wg, bg, lng, lnb, glob, Wsp, xs);
    out_kernel<<<1024, 256, 0, stream>>>(xs, masks, bsp, out);
}